// Round 13
// baseline (1230.018 us; speedup 1.0000x reference)
//
#include <hip/hip_runtime.h>

#define NN 16384
#define DD 128
#define KK 64
#define N_ITERS 10
#define NBLK 512          // k_sim blocks (row chunks)
#define RPB 32            // rows per block
#define RSTR 132          // padded row LDS stride (floats)
#define CSTR 132          // padded centroid LDS stride (floats)
#define EPSN 1e-12f
#define TOL2 1e-8f        // (1e-4)^2

typedef unsigned long long ull;

__device__ __forceinline__ bool gt_pair(float v, int i, float w, int j) {
  return (v > w) || (v == w && i < j);
}

__device__ __forceinline__ void merge2(float& b1, int& i1, float& b2, int& i2,
                                       float w1, int j1, float w2, int j2) {
  float v1, v2f; int n1, n2i;
  if (gt_pair(b1, i1, w1, j1)) {
    v1 = b1; n1 = i1;
    if (gt_pair(b2, i2, w1, j1)) { v2f = b2; n2i = i2; }
    else { v2f = w1; n2i = j1; }
  } else {
    v1 = w1; n1 = j1;
    if (gt_pair(b1, i1, w2, j2)) { v2f = b1; n2i = i1; }
    else { v2f = w2; n2i = j2; }
  }
  b1 = v1; i1 = n1; b2 = v2f; i2 = n2i;
}

// ---- re-arm tickets every call (graph replays don't re-poison ws)
__global__ __launch_bounds__(64) void k_zero(int* __restrict__ tickets) {
  if (threadIdx.x < 16) tickets[threadIdx.x] = 0;
}

// ---- fused sim/labels + (non-FINAL) ticket-gated reducer tail
//      (FINAL: negidx + per-block per-centroid top2)
template <int FINAL>
__global__ __launch_bounds__(256, 2) void k_sim(
    const float* __restrict__ E, const float* __restrict__ C0,
    const float* __restrict__ chatR, float* __restrict__ chatW,
    const float* __restrict__ cbPrev, float* __restrict__ cbW,
    float* __restrict__ upd, float* __restrict__ uhat,
    float* __restrict__ n2, int it,
    float* __restrict__ partial, int* __restrict__ pcountT,
    const float* __restrict__ cbSel, int* __restrict__ tickets,
    int* __restrict__ negidx, float* __restrict__ btvT, int* __restrict__ btiT,
    float* __restrict__ outc) {
  const int t = threadIdx.x;
  const int bid = blockIdx.x;
  __shared__ float csp[KK * CSTR];             // normalized centroids; acc overlay
  __shared__ float rowsL[RPB * RSTR];          // raw rows (padded)
  __shared__ float tile[FINAL ? RPB * 65 : 1]; // FINAL sim tile
  __shared__ float cinv0[KK];
  __shared__ int lab[RPB];
  __shared__ int s_sel;

  const int rloc = t >> 3;   // row slot 0..31
  const int sub = t & 7;     // 8 lanes per row

  // ---- stage rows to LDS (E read once per row)
  {
    const float4* rp = (const float4*)(E + (size_t)(bid * RPB + rloc) * DD);
    float4 a0 = rp[sub], a1 = rp[sub + 8], a2 = rp[sub + 16], a3 = rp[sub + 24];
    float4* rw = (float4*)(rowsL + rloc * RSTR);
    rw[sub] = a0; rw[sub + 8] = a1; rw[sub + 16] = a2; rw[sub + 24] = a3;
  }

  // ---- prologue: stage selected normalized centroids into csp
  if (it == 0) {
    for (int e = t; e < KK * DD; e += 256)
      csp[(e >> 7) * CSTR + (e & 127)] = C0[e];
    __syncthreads();
    if (t < KK) {
      const float4* cm = (const float4*)(csp + t * CSTR);
      float s = 0.f;
#pragma unroll
      for (int q = 0; q < 32; ++q) {
        float4 v = cm[q];
        s += v.x * v.x + v.y * v.y + v.z * v.z + v.w * v.w;
      }
      cinv0[t] = 1.0f / fmaxf(sqrtf(s), EPSN);
    }
    __syncthreads();
    for (int e = t; e < KK * DD; e += 256) {
      const int m = e >> 7, d = e & 127;
      float v = csp[m * CSTR + d] * cinv0[m];
      csp[m * CSTR + d] = v;
      if (bid == 0) chatW[e] = v;   // materialize chat_0
    }
  } else {
    if (t < KK) {
      bool ok = n2[t] < TOL2;
      ull mk = __ballot(ok);
      if (t == 0) s_sel = (mk == ~0ull) ? 1 : 0;
    }
    __syncthreads();
    const int sel = s_sel;
    const float* __restrict__ csrc = sel ? chatR : uhat;   // uniform pointer select
#pragma unroll 8
    for (int i = 0; i < 32; ++i) {
      const int e = i * 256 + t;
      csp[(e >> 7) * CSTR + (e & 127)] = csrc[e];
    }
    if (bid == 0) {
      const float* __restrict__ rsrc = sel ? cbPrev : upd;
      if (FINAL) {
#pragma unroll 8
        for (int i = 0; i < 32; ++i) {
          const int e = i * 256 + t;
          outc[e] = rsrc[e];
        }
      } else {
#pragma unroll 8
        for (int i = 0; i < 32; ++i) {
          const int e = i * 256 + t;
          chatW[e] = csrc[e];
          cbW[e] = rsrc[e];
        }
      }
    }
  }
  __syncthreads();

  // ---- pass1: row norm (exact ascending float4 order)
  const float4* rl = (const float4*)(rowsL + rloc * RSTR);
  float s = 0.f;
#pragma unroll
  for (int q = 0; q < 32; ++q) {
    float4 v = rl[q];
    s += v.x * v.x + v.y * v.y + v.z * v.z + v.w * v.w;
  }
  const float inv = 1.0f / fmaxf(sqrtf(s), EPSN);

  // ---- pass2: chunked dots, acc[8], q-ascending per (row,m)
  float acc[8];
#pragma unroll
  for (int cc = 0; cc < 8; ++cc) acc[cc] = 0.f;
#pragma unroll
  for (int ch = 0; ch < 4; ++ch) {
    float4 rv[8];
#pragma unroll
    for (int k = 0; k < 8; ++k) {
      float4 v = rl[ch * 8 + k];
      v.x *= inv; v.y *= inv; v.z *= inv; v.w *= inv;
      rv[k] = v;
    }
#pragma unroll
    for (int cc = 0; cc < 8; ++cc) {
      const int m = cc * 8 + sub;
      const float4* cp = (const float4*)(csp + m * CSTR) + ch * 8;
      float a = acc[cc];
#pragma unroll
      for (int k = 0; k < 8; ++k) {
        float4 cv = cp[k];
        a += rv[k].x * cv.x + rv[k].y * cv.y + rv[k].z * cv.z + rv[k].w * cv.w;
      }
      acc[cc] = a;
    }
  }
  if (FINAL) {
#pragma unroll
    for (int cc = 0; cc < 8; ++cc) tile[rloc * 65 + cc * 8 + sub] = acc[cc];
  }

  // ---- per-lane top2 (ascending m within lane), then 8-lane merge
  float b1 = -3.0e38f, b2 = -3.0e38f;
  int i1 = 0, i2 = 0;
#pragma unroll
  for (int cc = 0; cc < 8; ++cc) {
    const int m = cc * 8 + sub;
    const float a = acc[cc];
    if (a > b1) { b2 = b1; i2 = i1; b1 = a; i1 = m; }
    else if (a > b2) { b2 = a; i2 = m; }
  }
#pragma unroll
  for (int off = 1; off < 8; off <<= 1) {
    float w1 = __shfl_xor(b1, off);
    float w2 = __shfl_xor(b2, off);
    int j1 = __shfl_xor(i1, off);
    int j2 = __shfl_xor(i2, off);
    merge2(b1, i1, b2, i2, w1, j1, w2, j2);
  }

  if (!FINAL) {
    if (sub == 0) lab[rloc] = i1;
    __syncthreads();   // all csp reads (pass2) complete; lab visible below
    float* accL = csp; // overlay [64][128]
    for (int e = t; e < KK * DD; e += 256) accL[e] = 0.f;
    __syncthreads();
    if (t < 128) {
#pragma unroll 8
      for (int r = 0; r < RPB; ++r)
        accL[lab[r] * DD + t] += rowsL[r * RSTR + t];
    } else if (t < 192) {
      const int m = t - 128;
      int c = 0;
#pragma unroll
      for (int r = 0; r < RPB; ++r) c += (lab[r] == m) ? 1 : 0;
      pcountT[m * NBLK + bid] = c;
    }
    __syncthreads();
    float4* P4 = (float4*)(partial + (size_t)bid * (KK * DD));
    const float4* A4 = (const float4*)accL;
#pragma unroll
    for (int i = 0; i < 8; ++i) P4[i * 256 + t] = A4[i * 256 + t];

    // ---------- ticket-gated reducer tail (replaces k_red) ----------
    __threadfence();                 // release this block's partial/pcount stores
    __syncthreads();
    if (t == 0) s_sel = atomicAdd(&tickets[it], 1);
    __syncthreads();
    const int tk = s_sel;
    if (tk < NBLK - KK) return;      // not a reducer
    const int m = tk - (NBLK - KK);  // this block reduces centroid m
    if (t == 0) {
      while (atomicAdd(&tickets[it], 0) < NBLK) __builtin_amdgcn_s_sleep(2);
    }
    __syncthreads();
    __threadfence();                 // acquire all blocks' stores

    float* usL = csp;                // [128] overlay (acc dead)
    int* ciL = (int*)(csp + 128);    // [4]
    float* redL = csp + 136;         // [2]
    float* cinvL = csp + 140;        // [1]
    const int d = t & 127;

    // counts: integer, exact in any order
    int c = pcountT[m * NBLK + t] + pcountT[m * NBLK + 256 + t];
#pragma unroll
    for (int off = 1; off < 64; off <<= 1) c += __shfl_xor(c, off);
    if ((t & 63) == 0) ciL[t >> 6] = c;

    // float reduce, order identical to r11 k_red: per-group ascending j, groups ascending
    float stot = 0.f;
    if (t < 128) {
#pragma unroll
      for (int g = 0; g < 8; ++g) {
        float sg = 0.f;
#pragma unroll 16
        for (int j = 0; j < 64; ++j)
          sg += partial[(size_t)(g * 64 + j) * (KK * DD) + m * DD + d];
        stot += sg;
      }
    }
    __syncthreads();
    const int cnt = ((ciL[0] + ciL[1]) + ciL[2]) + ciL[3];
    if (t < 128) {
      const float cv = cbSel[m * DD + d];
      const float mean = (cnt > 0) ? (stot / fmaxf((float)cnt, 1.0f)) : cv;
      const float u = 0.1f * cv + 0.9f * mean;
      upd[m * DD + d] = u;
      usL[d] = u;
      const float diff = cv - u;
      float dsq = diff * diff;
#pragma unroll
      for (int off = 1; off < 64; off <<= 1) dsq += __shfl_xor(dsq, off);
      if ((t & 63) == 0) redL[t >> 6] = dsq;
    }
    __syncthreads();
    if (t == 0) {
      n2[m] = redL[0] + redL[1];
      const float4* u4 = (const float4*)usL;
      float ssq = 0.f;
#pragma unroll
      for (int q = 0; q < 32; ++q) {
        float4 v = u4[q];
        ssq += v.x * v.x + v.y * v.y + v.z * v.z + v.w * v.w;
      }
      cinvL[0] = 1.0f / fmaxf(sqrtf(ssq), EPSN);
    }
    __syncthreads();
    if (t < 128) uhat[m * DD + d] = usL[d] * cinvL[0];
  } else {
    if (sub == 0) negidx[bid * RPB + rloc] = i2;
    __syncthreads();
    if (t < KK) {
      const int m = t;
      float c1 = -3.0e38f, c2 = -3.0e38f;
      int j1 = -1, j2 = -1;
#pragma unroll 8
      for (int r = 0; r < RPB; ++r) {
        float v = tile[r * 65 + m];
        int gi = bid * RPB + r;
        if (v > c1) { c2 = c1; j2 = j1; c1 = v; j1 = gi; }
        else if (v > c2) { c2 = v; j2 = gi; }
      }
      btvT[(m * NBLK + bid) * 2 + 0] = c1;
      btvT[(m * NBLK + bid) * 2 + 1] = c2;
      btiT[(m * NBLK + bid) * 2 + 0] = j1;
      btiT[(m * NBLK + bid) * 2 + 1] = j2;
    }
  }
}

// ---- merge 512 per-block top-2 candidates per centroid
__global__ __launch_bounds__(256) void k_top(const float* __restrict__ btvT,
                                             const int* __restrict__ btiT,
                                             int* __restrict__ colti) {
  const int m = blockIdx.x, t = threadIdx.x;
  float b1 = btvT[(m * NBLK + t) * 2 + 0];
  float b2 = btvT[(m * NBLK + t) * 2 + 1];
  int i1 = btiT[(m * NBLK + t) * 2 + 0];
  int i2 = btiT[(m * NBLK + t) * 2 + 1];
  merge2(b1, i1, b2, i2,
         btvT[(m * NBLK + t + 256) * 2 + 0], btiT[(m * NBLK + t + 256) * 2 + 0],
         btvT[(m * NBLK + t + 256) * 2 + 1], btiT[(m * NBLK + t + 256) * 2 + 1]);
  __shared__ float s1[256], s2[256];
  __shared__ int t1[256], t2[256];
  s1[t] = b1; s2[t] = b2; t1[t] = i1; t2[t] = i2;
  __syncthreads();
  for (int o = 128; o > 0; o >>= 1) {
    if (t < o) {
      float a1 = s1[t], a2 = s2[t];
      int ai1 = t1[t], ai2 = t2[t];
      merge2(a1, ai1, a2, ai2, s1[t + o], t1[t + o], s2[t + o], t2[t + o]);
      s1[t] = a1; t1[t] = ai1; s2[t] = a2; t2[t] = ai2;
    }
    __syncthreads();
  }
  if (t == 0) {
    colti[2 * m] = t1[0];
    colti[2 * m + 1] = t2[0];
  }
}

// ---- gather negatives
__global__ __launch_bounds__(256) void k_gather(const float* __restrict__ E,
                                                const int* __restrict__ negidx,
                                                const int* __restrict__ colti,
                                                float* __restrict__ out) {
#pragma unroll
  for (int k = 0; k < 4; ++k) {
    int idx = (blockIdx.x * 4 + k) * 256 + threadIdx.x;
    int row = idx >> 7, d = idx & 127;
    int m = negidx[row];
    int j1 = colti[2 * m], j2 = colti[2 * m + 1];
    int j = (j1 != row) ? j1 : j2;
    out[(size_t)(KK * DD) + (size_t)row * DD + d] = E[(size_t)j * DD + d];
  }
}

extern "C" void kernel_launch(void* const* d_in, const int* in_sizes, int n_in,
                              void* d_out, int out_size, void* d_ws, size_t ws_size,
                              hipStream_t stream) {
  const float* E = (const float*)d_in[0];
  const float* C0 = (const float*)d_in[1];
  float* out = (float*)d_out;

  float* wsf = (float*)d_ws;
  float* chatG0 = wsf;                              // 8192
  float* chatG1 = chatG0 + KK * DD;                 // 8192
  float* cbb0 = chatG1 + KK * DD;                   // 8192
  float* cbb1 = cbb0 + KK * DD;                     // 8192
  float* updb = cbb1 + KK * DD;                     // 8192
  float* uhat = updb + KK * DD;                     // 8192
  float* n2b = uhat + KK * DD;                      // 64
  float* partial = n2b + KK;                        // [512][64][128] = 16 MB
  int* pcountT = (int*)(partial + (size_t)NBLK * KK * DD);  // 64*512
  int* tickets = pcountT + KK * NBLK;               // 16
  int* negidx = tickets + 16;                       // NN
  int* colti = negidx + NN;                         // 128
  float* btvT = (float*)(colti + 128);              // 64*512*2
  int* btiT = (int*)(btvT + KK * NBLK * 2);         // 64*512*2

  float* chatG[2] = {chatG0, chatG1};
  float* cbb[2] = {cbb0, cbb1};

  k_zero<<<1, 64, 0, stream>>>(tickets);

  for (int it = 0; it < N_ITERS; ++it) {
    const float* chatR = (it == 0) ? chatG0 : chatG[(it - 1) & 1];
    float* chatW = chatG[it & 1];
    const float* cbPrev = (it <= 1) ? C0 : cbb[(it - 1) & 1];
    float* cbW = cbb[it & 1];
    const float* cbSel = (it == 0) ? C0 : cbW;   // raw c_t for this iter's update
    k_sim<0><<<NBLK, 256, 0, stream>>>(E, C0, chatR, chatW, cbPrev, cbW, updb,
                                       uhat, n2b, it, partial, pcountT,
                                       cbSel, tickets,
                                       nullptr, nullptr, nullptr, nullptr);
  }
  // final: select c_10 (block0 -> out), sim, negidx, per-block top2
  k_sim<1><<<NBLK, 256, 0, stream>>>(E, C0, chatG[(N_ITERS - 1) & 1], nullptr,
                                     cbb[(N_ITERS - 1) & 1], nullptr, updb, uhat,
                                     n2b, N_ITERS, nullptr, nullptr,
                                     nullptr, nullptr,
                                     negidx, btvT, btiT, out);
  k_top<<<KK, 256, 0, stream>>>(btvT, btiT, colti);
  k_gather<<<NN * DD / 1024, 256, 0, stream>>>(E, negidx, colti, out);
}

// Round 14
// 284.072 us; speedup vs baseline: 4.3300x; 4.3300x over previous
//
#include <hip/hip_runtime.h>

#define NN 16384
#define DD 128
#define KK 64
#define N_ITERS 10
#define NBLK 512          // k_sim blocks (row chunks)
#define RPB 32            // rows per block
#define RSTR 132          // padded row LDS stride (floats)
#define CSTR 132          // padded centroid LDS stride (floats)
#define EPSN 1e-12f
#define TOL2 1e-8f        // (1e-4)^2

typedef unsigned long long ull;

__device__ __forceinline__ bool gt_pair(float v, int i, float w, int j) {
  return (v > w) || (v == w && i < j);
}

__device__ __forceinline__ void merge2(float& b1, int& i1, float& b2, int& i2,
                                       float w1, int j1, float w2, int j2) {
  float v1, v2f; int n1, n2i;
  if (gt_pair(b1, i1, w1, j1)) {
    v1 = b1; n1 = i1;
    if (gt_pair(b2, i2, w1, j1)) { v2f = b2; n2i = i2; }
    else { v2f = w1; n2i = j1; }
  } else {
    v1 = w1; n1 = j1;
    if (gt_pair(b1, i1, w2, j2)) { v2f = b1; n2i = i1; }
    else { v2f = w2; n2i = j2; }
  }
  b1 = v1; i1 = n1; b2 = v2f; i2 = n2i;
}

// ---- fused sim/labels (+FINAL: negidx + per-block per-centroid top2)
// dot phase: 16 lanes per ROW-PAIR, 4 centroids/lane, 2 rows/thread
// (each centroid float4 load feeds 2 rows -> centroid LDS traffic halved)
template <int FINAL>
__global__ __launch_bounds__(256, 2) void k_sim(
    const float* __restrict__ E, const float* __restrict__ C0,
    const float* __restrict__ chatR, float* __restrict__ chatW,
    const float* __restrict__ cbPrev, float* __restrict__ cbW,
    const float* __restrict__ upd, const float* __restrict__ uhat,
    const float* __restrict__ n2, int it,
    float* __restrict__ partial, int* __restrict__ pcountT,
    int* __restrict__ negidx, float* __restrict__ btvT, int* __restrict__ btiT,
    float* __restrict__ outc) {
  const int t = threadIdx.x;
  const int bid = blockIdx.x;
  __shared__ float csp[KK * CSTR];             // normalized centroids; acc overlay
  __shared__ float rowsL[RPB * RSTR];          // raw rows (padded)
  __shared__ float tile[FINAL ? RPB * 65 : 1]; // FINAL sim tile
  __shared__ float cinv0[KK];
  __shared__ int lab[RPB];
  __shared__ int s_sel;

  // ---- stage rows to LDS (identical access pattern to r11)
  {
    const int srow = t >> 3, sq = t & 7;
    const float4* rp = (const float4*)(E + (size_t)(bid * RPB + srow) * DD);
    float4 a0 = rp[sq], a1 = rp[sq + 8], a2 = rp[sq + 16], a3 = rp[sq + 24];
    float4* rw = (float4*)(rowsL + srow * RSTR);
    rw[sq] = a0; rw[sq + 8] = a1; rw[sq + 16] = a2; rw[sq + 24] = a3;
  }

  // ---- prologue: stage selected normalized centroids into csp
  if (it == 0) {
    for (int e = t; e < KK * DD; e += 256)
      csp[(e >> 7) * CSTR + (e & 127)] = C0[e];
    __syncthreads();
    if (t < KK) {
      const float4* cm = (const float4*)(csp + t * CSTR);
      float s = 0.f;
#pragma unroll
      for (int q = 0; q < 32; ++q) {
        float4 v = cm[q];
        s += v.x * v.x + v.y * v.y + v.z * v.z + v.w * v.w;
      }
      cinv0[t] = 1.0f / fmaxf(sqrtf(s), EPSN);
    }
    __syncthreads();
    for (int e = t; e < KK * DD; e += 256) {
      const int m = e >> 7, d = e & 127;
      float v = csp[m * CSTR + d] * cinv0[m];
      csp[m * CSTR + d] = v;
      if (bid == 0) chatW[e] = v;   // materialize chat_0
    }
  } else {
    if (t < KK) {
      bool ok = n2[t] < TOL2;
      ull mk = __ballot(ok);
      if (t == 0) s_sel = (mk == ~0ull) ? 1 : 0;
    }
    __syncthreads();
    const int sel = s_sel;
    const float* __restrict__ csrc = sel ? chatR : uhat;   // uniform pointer select
#pragma unroll 8
    for (int i = 0; i < 32; ++i) {
      const int e = i * 256 + t;
      csp[(e >> 7) * CSTR + (e & 127)] = csrc[e];
    }
    if (bid == 0) {
      const float* __restrict__ rsrc = sel ? cbPrev : upd;
      if (FINAL) {
#pragma unroll 8
        for (int i = 0; i < 32; ++i) {
          const int e = i * 256 + t;
          outc[e] = rsrc[e];
        }
      } else {
#pragma unroll 8
        for (int i = 0; i < 32; ++i) {
          const int e = i * 256 + t;
          chatW[e] = csrc[e];
          cbW[e] = rsrc[e];
        }
      }
    }
  }
  __syncthreads();

  // ---- geometry: 16 lanes per row-pair
  const int pg = t >> 4;        // pair group 0..15
  const int sub = t & 15;       // lane in group
  const int rA = pg * 2, rB = pg * 2 + 1;

  // ---- pass1: split norm (lanes sub<8 do row A, sub>=8 row B; exact ascending order)
  {
    const int myRow = (sub < 8) ? rA : rB;
    const float4* rlM = (const float4*)(rowsL + myRow * RSTR);
    float s = 0.f;
#pragma unroll
    for (int q = 0; q < 32; ++q) {
      float4 v = rlM[q];
      s += v.x * v.x + v.y * v.y + v.z * v.z + v.w * v.w;
    }
    float invM = 1.0f / fmaxf(sqrtf(s), EPSN);
    const int gb = (t & 63) & ~15;
    float invA = __shfl(invM, gb);
    float invB = __shfl(invM, gb + 8);

    // ---- pass2: chunked dots, 2 rows x 4 centroids, k/ch ascending per (row,m)
    const float4* rlA = (const float4*)(rowsL + rA * RSTR);
    const float4* rlB = (const float4*)(rowsL + rB * RSTR);
    float accA[4], accB[4];
#pragma unroll
    for (int cc = 0; cc < 4; ++cc) { accA[cc] = 0.f; accB[cc] = 0.f; }
#pragma unroll
    for (int ch = 0; ch < 4; ++ch) {
      float4 ra[8], rb[8];
#pragma unroll
      for (int k = 0; k < 8; ++k) {
        float4 va = rlA[ch * 8 + k];
        va.x *= invA; va.y *= invA; va.z *= invA; va.w *= invA;
        ra[k] = va;
        float4 vb = rlB[ch * 8 + k];
        vb.x *= invB; vb.y *= invB; vb.z *= invB; vb.w *= invB;
        rb[k] = vb;
      }
#pragma unroll
      for (int cc = 0; cc < 4; ++cc) {
        const int m = cc * 16 + sub;
        const float4* cp = (const float4*)(csp + m * CSTR) + ch * 8;
        float aA = accA[cc], aB = accB[cc];
#pragma unroll
        for (int k = 0; k < 8; ++k) {
          float4 cv = cp[k];
          aA += ra[k].x * cv.x + ra[k].y * cv.y + ra[k].z * cv.z + ra[k].w * cv.w;
          aB += rb[k].x * cv.x + rb[k].y * cv.y + rb[k].z * cv.z + rb[k].w * cv.w;
        }
        accA[cc] = aA; accB[cc] = aB;
      }
    }
    if (FINAL) {
#pragma unroll
      for (int cc = 0; cc < 4; ++cc) {
        tile[rA * 65 + cc * 16 + sub] = accA[cc];
        tile[rB * 65 + cc * 16 + sub] = accB[cc];
      }
    }

    // ---- per-lane top2 (ascending m within lane), then 16-lane merge, both rows
    float b1A = -3.0e38f, b2A = -3.0e38f, b1B = -3.0e38f, b2B = -3.0e38f;
    int i1A = 0, i2A = 0, i1B = 0, i2B = 0;
#pragma unroll
    for (int cc = 0; cc < 4; ++cc) {
      const int m = cc * 16 + sub;
      const float aA = accA[cc];
      if (aA > b1A) { b2A = b1A; i2A = i1A; b1A = aA; i1A = m; }
      else if (aA > b2A) { b2A = aA; i2A = m; }
      const float aB = accB[cc];
      if (aB > b1B) { b2B = b1B; i2B = i1B; b1B = aB; i1B = m; }
      else if (aB > b2B) { b2B = aB; i2B = m; }
    }
#pragma unroll
    for (int off = 1; off < 16; off <<= 1) {
      float w1 = __shfl_xor(b1A, off), w2 = __shfl_xor(b2A, off);
      int j1 = __shfl_xor(i1A, off), j2 = __shfl_xor(i2A, off);
      merge2(b1A, i1A, b2A, i2A, w1, j1, w2, j2);
      w1 = __shfl_xor(b1B, off); w2 = __shfl_xor(b2B, off);
      j1 = __shfl_xor(i1B, off); j2 = __shfl_xor(i2B, off);
      merge2(b1B, i1B, b2B, i2B, w1, j1, w2, j2);
    }

    if (!FINAL) {
      if (sub == 0) { lab[rA] = i1A; lab[rB] = i1B; }
    } else {
      if (sub == 0) {
        negidx[bid * RPB + rA] = i2A;
        negidx[bid * RPB + rB] = i2B;
      }
    }
  }

  if (!FINAL) {
    __syncthreads();   // all csp reads (pass2) complete; lab visible below
    float* accL = csp; // overlay [64][128]
    for (int e = t; e < KK * DD; e += 256) accL[e] = 0.f;
    __syncthreads();
    if (t < 128) {
#pragma unroll 8
      for (int r = 0; r < RPB; ++r)
        accL[lab[r] * DD + t] += rowsL[r * RSTR + t];
    } else if (t < 192) {
      const int m = t - 128;
      int c = 0;
#pragma unroll
      for (int r = 0; r < RPB; ++r) c += (lab[r] == m) ? 1 : 0;
      pcountT[m * NBLK + bid] = c;
    }
    __syncthreads();
    float4* P4 = (float4*)(partial + (size_t)bid * (KK * DD));
    const float4* A4 = (const float4*)accL;
#pragma unroll
    for (int i = 0; i < 8; ++i) P4[i * 256 + t] = A4[i * 256 + t];
  } else {
    __syncthreads();   // tile fully written
    if (t < KK) {
      const int m = t;
      float c1 = -3.0e38f, c2 = -3.0e38f;
      int j1 = -1, j2 = -1;
#pragma unroll 8
      for (int r = 0; r < RPB; ++r) {
        float v = tile[r * 65 + m];
        int gi = bid * RPB + r;
        if (v > c1) { c2 = c1; j2 = j1; c1 = v; j1 = gi; }
        else if (v > c2) { c2 = v; j2 = gi; }
      }
      btvT[(m * NBLK + bid) * 2 + 0] = c1;
      btvT[(m * NBLK + bid) * 2 + 1] = c2;
      btiT[(m * NBLK + bid) * 2 + 0] = j1;
      btiT[(m * NBLK + bid) * 2 + 1] = j2;
    }
  }
}

// ---- per-centroid: reduce 512 partials -> upd, n2, uhat=normalize(upd)
__global__ __launch_bounds__(1024) void k_red(
    const float* __restrict__ cbR,
    const float* __restrict__ partial, const int* __restrict__ pcountT,
    float* __restrict__ upd, float* __restrict__ uhat, float* __restrict__ n2) {
  const int m = blockIdx.x, t = threadIdx.x;
  const int g = t >> 7, d = t & 127;   // 8 groups x 64 chunks
  __shared__ float sh[8][DD];
  __shared__ float us[DD];
  __shared__ int ci[8];
  __shared__ float redv[2];
  __shared__ float s_cinv;

  float s = 0.f;
#pragma unroll 8
  for (int j = 0; j < NBLK / 8; ++j)
    s += partial[(size_t)(g * (NBLK / 8) + j) * (KK * DD) + m * DD + d];
  sh[g][d] = s;

  int c = 0;
  if (t < NBLK) c = pcountT[m * NBLK + t];
#pragma unroll
  for (int off = 1; off < 64; off <<= 1) c += __shfl_xor(c, off);
  if (t < NBLK && (t & 63) == 0) ci[t >> 6] = c;
  __syncthreads();
  const int cnt = ((((((ci[0] + ci[1]) + ci[2]) + ci[3]) + ci[4]) + ci[5]) + ci[6]) + ci[7];

  if (t < 128) {
    float stot = sh[0][d];
#pragma unroll
    for (int k = 1; k < 8; ++k) stot += sh[k][d];
    const float cv = cbR[m * DD + d];
    const float mean = (cnt > 0) ? (stot / fmaxf((float)cnt, 1.0f)) : cv;
    const float u = 0.1f * cv + 0.9f * mean;
    upd[m * DD + d] = u;
    us[d] = u;
    const float diff = cv - u;
    float dsq = diff * diff;
#pragma unroll
    for (int off = 1; off < 64; off <<= 1) dsq += __shfl_xor(dsq, off);
    if ((t & 63) == 0) redv[t >> 6] = dsq;
  }
  __syncthreads();
  if (t == 0) {
    n2[m] = redv[0] + redv[1];
    const float4* u4 = (const float4*)us;
    float ssq = 0.f;
#pragma unroll
    for (int q = 0; q < 32; ++q) {
      float4 v = u4[q];
      ssq += v.x * v.x + v.y * v.y + v.z * v.z + v.w * v.w;
    }
    s_cinv = 1.0f / fmaxf(sqrtf(ssq), EPSN);
  }
  __syncthreads();
  if (t < 128) uhat[m * DD + d] = us[d] * s_cinv;
}

// ---- merge 512 per-block top-2 candidates per centroid
__global__ __launch_bounds__(256) void k_top(const float* __restrict__ btvT,
                                             const int* __restrict__ btiT,
                                             int* __restrict__ colti) {
  const int m = blockIdx.x, t = threadIdx.x;
  float b1 = btvT[(m * NBLK + t) * 2 + 0];
  float b2 = btvT[(m * NBLK + t) * 2 + 1];
  int i1 = btiT[(m * NBLK + t) * 2 + 0];
  int i2 = btiT[(m * NBLK + t) * 2 + 1];
  merge2(b1, i1, b2, i2,
         btvT[(m * NBLK + t + 256) * 2 + 0], btiT[(m * NBLK + t + 256) * 2 + 0],
         btvT[(m * NBLK + t + 256) * 2 + 1], btiT[(m * NBLK + t + 256) * 2 + 1]);
  __shared__ float s1[256], s2[256];
  __shared__ int t1[256], t2[256];
  s1[t] = b1; s2[t] = b2; t1[t] = i1; t2[t] = i2;
  __syncthreads();
  for (int o = 128; o > 0; o >>= 1) {
    if (t < o) {
      float a1 = s1[t], a2 = s2[t];
      int ai1 = t1[t], ai2 = t2[t];
      merge2(a1, ai1, a2, ai2, s1[t + o], t1[t + o], s2[t + o], t2[t + o]);
      s1[t] = a1; t1[t] = ai1; s2[t] = a2; t2[t] = ai2;
    }
    __syncthreads();
  }
  if (t == 0) {
    colti[2 * m] = t1[0];
    colti[2 * m + 1] = t2[0];
  }
}

// ---- gather negatives
__global__ __launch_bounds__(256) void k_gather(const float* __restrict__ E,
                                                const int* __restrict__ negidx,
                                                const int* __restrict__ colti,
                                                float* __restrict__ out) {
#pragma unroll
  for (int k = 0; k < 4; ++k) {
    int idx = (blockIdx.x * 4 + k) * 256 + threadIdx.x;
    int row = idx >> 7, d = idx & 127;
    int m = negidx[row];
    int j1 = colti[2 * m], j2 = colti[2 * m + 1];
    int j = (j1 != row) ? j1 : j2;
    out[(size_t)(KK * DD) + (size_t)row * DD + d] = E[(size_t)j * DD + d];
  }
}

extern "C" void kernel_launch(void* const* d_in, const int* in_sizes, int n_in,
                              void* d_out, int out_size, void* d_ws, size_t ws_size,
                              hipStream_t stream) {
  const float* E = (const float*)d_in[0];
  const float* C0 = (const float*)d_in[1];
  float* out = (float*)d_out;

  float* wsf = (float*)d_ws;
  float* chatG0 = wsf;                              // 8192
  float* chatG1 = chatG0 + KK * DD;                 // 8192
  float* cbb0 = chatG1 + KK * DD;                   // 8192
  float* cbb1 = cbb0 + KK * DD;                     // 8192
  float* updb = cbb1 + KK * DD;                     // 8192
  float* uhat = updb + KK * DD;                     // 8192
  float* n2b = uhat + KK * DD;                      // 64
  float* partial = n2b + KK;                        // [512][64][128] = 16 MB
  int* pcountT = (int*)(partial + (size_t)NBLK * KK * DD);  // 64*512
  int* negidx = pcountT + KK * NBLK;                // NN
  int* colti = negidx + NN;                         // 128
  float* btvT = (float*)(colti + 128);              // 64*512*2
  int* btiT = (int*)(btvT + KK * NBLK * 2);         // 64*512*2

  float* chatG[2] = {chatG0, chatG1};
  float* cbb[2] = {cbb0, cbb1};

  for (int it = 0; it < N_ITERS; ++it) {
    const float* chatR = (it == 0) ? chatG0 : chatG[(it - 1) & 1];
    float* chatW = chatG[it & 1];
    const float* cbPrev = (it <= 1) ? C0 : cbb[(it - 1) & 1];
    float* cbW = cbb[it & 1];
    k_sim<0><<<NBLK, 256, 0, stream>>>(E, C0, chatR, chatW, cbPrev, cbW, updb,
                                       uhat, n2b, it, partial, pcountT,
                                       nullptr, nullptr, nullptr, nullptr);
    const float* cbR = (it == 0) ? C0 : cbb[it & 1];
    k_red<<<KK, 1024, 0, stream>>>(cbR, partial, pcountT, updb, uhat, n2b);
  }
  // final: select c_10 (block0 -> out), sim, negidx, per-block top2
  k_sim<1><<<NBLK, 256, 0, stream>>>(E, C0, chatG[(N_ITERS - 1) & 1], nullptr,
                                     cbb[(N_ITERS - 1) & 1], nullptr, updb, uhat,
                                     n2b, N_ITERS, nullptr, nullptr,
                                     negidx, btvT, btiT, out);
  k_top<<<KK, 256, 0, stream>>>(btvT, btiT, colti);
  k_gather<<<NN * DD / 1024, 256, 0, stream>>>(E, negidx, colti, out);
}

// Round 15
// 279.299 us; speedup vs baseline: 4.4040x; 1.0171x over previous
//
#include <hip/hip_runtime.h>

#define NN 16384
#define DD 128
#define KK 64
#define N_ITERS 10
#define NBLK 512          // k_sim blocks (row chunks)
#define RPB 32            // rows per block
#define RSTR 132          // padded row LDS stride (floats)
#define CSTR 132          // padded centroid LDS stride (floats)
#define EPSN 1e-12f
#define TOL2 1e-8f        // (1e-4)^2

typedef unsigned long long ull;

__device__ __forceinline__ bool gt_pair(float v, int i, float w, int j) {
  return (v > w) || (v == w && i < j);
}

__device__ __forceinline__ void merge2(float& b1, int& i1, float& b2, int& i2,
                                       float w1, int j1, float w2, int j2) {
  float v1, v2f; int n1, n2i;
  if (gt_pair(b1, i1, w1, j1)) {
    v1 = b1; n1 = i1;
    if (gt_pair(b2, i2, w1, j1)) { v2f = b2; n2i = i2; }
    else { v2f = w1; n2i = j1; }
  } else {
    v1 = w1; n1 = j1;
    if (gt_pair(b1, i1, w2, j2)) { v2f = b1; n2i = i1; }
    else { v2f = w2; n2i = j2; }
  }
  b1 = v1; i1 = n1; b2 = v2f; i2 = n2i;
}

// ---- fused sim/labels (+FINAL: negidx + per-block per-centroid top2)
// dot phase: 16 lanes per ROW-PAIR, 4 centroids/lane, 2 rows/thread.
// row norm fused into staging (register squares + 8-lane butterfly).
template <int FINAL>
__global__ __launch_bounds__(256, 2) void k_sim(
    const float* __restrict__ E, const float* __restrict__ C0,
    const float* __restrict__ chatR, float* __restrict__ chatW,
    const float* __restrict__ cbPrev, float* __restrict__ cbW,
    const float* __restrict__ upd, const float* __restrict__ uhat,
    const float* __restrict__ n2, int it,
    float* __restrict__ partial, int* __restrict__ pcountT,
    int* __restrict__ negidx, float* __restrict__ btvT, int* __restrict__ btiT,
    float* __restrict__ outc) {
  const int t = threadIdx.x;
  const int bid = blockIdx.x;
  __shared__ float csp[KK * CSTR];             // normalized centroids; acc overlay
  __shared__ float rowsL[RPB * RSTR];          // raw rows (padded)
  __shared__ float tile[FINAL ? RPB * 65 : 1]; // FINAL sim tile
  __shared__ float cinv0[KK];
  __shared__ int lab[RPB];
  __shared__ int s_sel;

  // ---- stage rows to LDS + fused norm partial (squares from registers)
  float s_part;
  {
    const int srow = t >> 3, sq = t & 7;
    const float4* rp = (const float4*)(E + (size_t)(bid * RPB + srow) * DD);
    float4 a0 = rp[sq], a1 = rp[sq + 8], a2 = rp[sq + 16], a3 = rp[sq + 24];
    s_part = a0.x * a0.x + a0.y * a0.y + a0.z * a0.z + a0.w * a0.w
           + a1.x * a1.x + a1.y * a1.y + a1.z * a1.z + a1.w * a1.w
           + a2.x * a2.x + a2.y * a2.y + a2.z * a2.z + a2.w * a2.w
           + a3.x * a3.x + a3.y * a3.y + a3.z * a3.z + a3.w * a3.w;
    float4* rw = (float4*)(rowsL + srow * RSTR);
    rw[sq] = a0; rw[sq + 8] = a1; rw[sq + 16] = a2; rw[sq + 24] = a3;
  }
  // 8-lane butterfly (aligned group; commutative adds -> lane-identical, deterministic)
#pragma unroll
  for (int off = 1; off < 8; off <<= 1) s_part += __shfl_xor(s_part, off);
  const float invM = 1.0f / fmaxf(sqrtf(s_part), EPSN);
  const int gb = (t & 63) & ~15;
  const float invA = __shfl(invM, gb);        // inv of even staged row (rA)
  const float invB = __shfl(invM, gb + 8);    // inv of odd staged row (rB)

  // ---- prologue: stage selected normalized centroids into csp (vectorized)
  if (it == 0) {
    for (int e4 = t; e4 < KK * DD / 4; e4 += 256)
      ((float4*)csp)[(e4 >> 5) * (CSTR / 4) + (e4 & 31)] = ((const float4*)C0)[e4];
    __syncthreads();
    if (t < KK) {
      const float4* cm = (const float4*)(csp + t * CSTR);
      float s = 0.f;
#pragma unroll
      for (int q = 0; q < 32; ++q) {
        float4 v = cm[q];
        s += v.x * v.x + v.y * v.y + v.z * v.z + v.w * v.w;
      }
      cinv0[t] = 1.0f / fmaxf(sqrtf(s), EPSN);
    }
    __syncthreads();
    for (int e = t; e < KK * DD; e += 256) {
      const int m = e >> 7, d = e & 127;
      float v = csp[m * CSTR + d] * cinv0[m];
      csp[m * CSTR + d] = v;
      if (bid == 0) chatW[e] = v;   // materialize chat_0
    }
  } else {
    if (t < KK) {
      bool ok = n2[t] < TOL2;
      ull mk = __ballot(ok);
      if (t == 0) s_sel = (mk == ~0ull) ? 1 : 0;
    }
    __syncthreads();
    const int sel = s_sel;
    const float4* __restrict__ csrc4 = (const float4*)(sel ? chatR : uhat);
#pragma unroll
    for (int i = 0; i < 8; ++i) {
      const int e4 = i * 256 + t;
      ((float4*)csp)[(e4 >> 5) * (CSTR / 4) + (e4 & 31)] = csrc4[e4];
    }
    if (bid == 0) {
      const float4* __restrict__ rsrc4 = (const float4*)(sel ? cbPrev : upd);
      if (FINAL) {
#pragma unroll
        for (int i = 0; i < 8; ++i) {
          const int e4 = i * 256 + t;
          ((float4*)outc)[e4] = rsrc4[e4];
        }
      } else {
#pragma unroll
        for (int i = 0; i < 8; ++i) {
          const int e4 = i * 256 + t;
          ((float4*)chatW)[e4] = csrc4[e4];
          ((float4*)cbW)[e4] = rsrc4[e4];
        }
      }
    }
  }
  __syncthreads();

  // ---- geometry: 16 lanes per row-pair
  const int pg = t >> 4;        // pair group 0..15
  const int sub = t & 15;       // lane in group
  const int rA = pg * 2, rB = pg * 2 + 1;

  {
    // ---- pass2: chunked dots, 2 rows x 4 centroids, k/ch ascending per (row,m)
    const float4* rlA = (const float4*)(rowsL + rA * RSTR);
    const float4* rlB = (const float4*)(rowsL + rB * RSTR);
    float accA[4], accB[4];
#pragma unroll
    for (int cc = 0; cc < 4; ++cc) { accA[cc] = 0.f; accB[cc] = 0.f; }
#pragma unroll
    for (int ch = 0; ch < 4; ++ch) {
      float4 ra[8], rb[8];
#pragma unroll
      for (int k = 0; k < 8; ++k) {
        float4 va = rlA[ch * 8 + k];
        va.x *= invA; va.y *= invA; va.z *= invA; va.w *= invA;
        ra[k] = va;
        float4 vb = rlB[ch * 8 + k];
        vb.x *= invB; vb.y *= invB; vb.z *= invB; vb.w *= invB;
        rb[k] = vb;
      }
#pragma unroll
      for (int cc = 0; cc < 4; ++cc) {
        const int m = cc * 16 + sub;
        const float4* cp = (const float4*)(csp + m * CSTR) + ch * 8;
        float aA = accA[cc], aB = accB[cc];
#pragma unroll
        for (int k = 0; k < 8; ++k) {
          float4 cv = cp[k];
          aA += ra[k].x * cv.x + ra[k].y * cv.y + ra[k].z * cv.z + ra[k].w * cv.w;
          aB += rb[k].x * cv.x + rb[k].y * cv.y + rb[k].z * cv.z + rb[k].w * cv.w;
        }
        accA[cc] = aA; accB[cc] = aB;
      }
    }
    if (FINAL) {
#pragma unroll
      for (int cc = 0; cc < 4; ++cc) {
        tile[rA * 65 + cc * 16 + sub] = accA[cc];
        tile[rB * 65 + cc * 16 + sub] = accB[cc];
      }
    }

    // ---- per-lane top2 (ascending m within lane), then 16-lane merge, both rows
    float b1A = -3.0e38f, b2A = -3.0e38f, b1B = -3.0e38f, b2B = -3.0e38f;
    int i1A = 0, i2A = 0, i1B = 0, i2B = 0;
#pragma unroll
    for (int cc = 0; cc < 4; ++cc) {
      const int m = cc * 16 + sub;
      const float aA = accA[cc];
      if (aA > b1A) { b2A = b1A; i2A = i1A; b1A = aA; i1A = m; }
      else if (aA > b2A) { b2A = aA; i2A = m; }
      const float aB = accB[cc];
      if (aB > b1B) { b2B = b1B; i2B = i1B; b1B = aB; i1B = m; }
      else if (aB > b2B) { b2B = aB; i2B = m; }
    }
#pragma unroll
    for (int off = 1; off < 16; off <<= 1) {
      float w1 = __shfl_xor(b1A, off), w2 = __shfl_xor(b2A, off);
      int j1 = __shfl_xor(i1A, off), j2 = __shfl_xor(i2A, off);
      merge2(b1A, i1A, b2A, i2A, w1, j1, w2, j2);
      w1 = __shfl_xor(b1B, off); w2 = __shfl_xor(b2B, off);
      j1 = __shfl_xor(i1B, off); j2 = __shfl_xor(i2B, off);
      merge2(b1B, i1B, b2B, i2B, w1, j1, w2, j2);
    }

    if (!FINAL) {
      if (sub == 0) { lab[rA] = i1A; lab[rB] = i1B; }
    } else {
      if (sub == 0) {
        negidx[bid * RPB + rA] = i2A;
        negidx[bid * RPB + rB] = i2B;
      }
    }
  }

  if (!FINAL) {
    __syncthreads();   // all csp reads (pass2) complete; lab visible below
    float* accL = csp; // overlay [64][128]
    for (int e = t; e < KK * DD; e += 256) accL[e] = 0.f;
    __syncthreads();
    if (t < 128) {
#pragma unroll 8
      for (int r = 0; r < RPB; ++r)
        accL[lab[r] * DD + t] += rowsL[r * RSTR + t];
    } else if (t < 192) {
      const int m = t - 128;
      int c = 0;
#pragma unroll
      for (int r = 0; r < RPB; ++r) c += (lab[r] == m) ? 1 : 0;
      pcountT[m * NBLK + bid] = c;
    }
    __syncthreads();
    float4* P4 = (float4*)(partial + (size_t)bid * (KK * DD));
    const float4* A4 = (const float4*)accL;
#pragma unroll
    for (int i = 0; i < 8; ++i) P4[i * 256 + t] = A4[i * 256 + t];
  } else {
    __syncthreads();   // tile fully written
    if (t < KK) {
      const int m = t;
      float c1 = -3.0e38f, c2 = -3.0e38f;
      int j1 = -1, j2 = -1;
#pragma unroll 8
      for (int r = 0; r < RPB; ++r) {
        float v = tile[r * 65 + m];
        int gi = bid * RPB + r;
        if (v > c1) { c2 = c1; j2 = j1; c1 = v; j1 = gi; }
        else if (v > c2) { c2 = v; j2 = gi; }
      }
      btvT[(m * NBLK + bid) * 2 + 0] = c1;
      btvT[(m * NBLK + bid) * 2 + 1] = c2;
      btiT[(m * NBLK + bid) * 2 + 0] = j1;
      btiT[(m * NBLK + bid) * 2 + 1] = j2;
    }
  }
}

// ---- per-centroid: reduce 512 partials -> upd, n2, uhat=normalize(upd)
__global__ __launch_bounds__(1024) void k_red(
    const float* __restrict__ cbR,
    const float* __restrict__ partial, const int* __restrict__ pcountT,
    float* __restrict__ upd, float* __restrict__ uhat, float* __restrict__ n2) {
  const int m = blockIdx.x, t = threadIdx.x;
  const int g = t >> 7, d = t & 127;   // 8 groups x 64 chunks
  __shared__ float sh[8][DD];
  __shared__ float us[DD];
  __shared__ int ci[8];
  __shared__ float redv[2];
  __shared__ float s_cinv;

  float s = 0.f;
#pragma unroll 8
  for (int j = 0; j < NBLK / 8; ++j)
    s += partial[(size_t)(g * (NBLK / 8) + j) * (KK * DD) + m * DD + d];
  sh[g][d] = s;

  int c = 0;
  if (t < NBLK) c = pcountT[m * NBLK + t];
#pragma unroll
  for (int off = 1; off < 64; off <<= 1) c += __shfl_xor(c, off);
  if (t < NBLK && (t & 63) == 0) ci[t >> 6] = c;
  __syncthreads();
  const int cnt = ((((((ci[0] + ci[1]) + ci[2]) + ci[3]) + ci[4]) + ci[5]) + ci[6]) + ci[7];

  if (t < 128) {
    float stot = sh[0][d];
#pragma unroll
    for (int k = 1; k < 8; ++k) stot += sh[k][d];
    const float cv = cbR[m * DD + d];
    const float mean = (cnt > 0) ? (stot / fmaxf((float)cnt, 1.0f)) : cv;
    const float u = 0.1f * cv + 0.9f * mean;
    upd[m * DD + d] = u;
    us[d] = u;
    const float diff = cv - u;
    float dsq = diff * diff;
#pragma unroll
    for (int off = 1; off < 64; off <<= 1) dsq += __shfl_xor(dsq, off);
    if ((t & 63) == 0) redv[t >> 6] = dsq;
  }
  __syncthreads();
  if (t == 0) {
    n2[m] = redv[0] + redv[1];
    const float4* u4 = (const float4*)us;
    float ssq = 0.f;
#pragma unroll
    for (int q = 0; q < 32; ++q) {
      float4 v = u4[q];
      ssq += v.x * v.x + v.y * v.y + v.z * v.z + v.w * v.w;
    }
    s_cinv = 1.0f / fmaxf(sqrtf(ssq), EPSN);
  }
  __syncthreads();
  if (t < 128) uhat[m * DD + d] = us[d] * s_cinv;
}

// ---- merge 512 per-block top-2 candidates per centroid
__global__ __launch_bounds__(256) void k_top(const float* __restrict__ btvT,
                                             const int* __restrict__ btiT,
                                             int* __restrict__ colti) {
  const int m = blockIdx.x, t = threadIdx.x;
  float b1 = btvT[(m * NBLK + t) * 2 + 0];
  float b2 = btvT[(m * NBLK + t) * 2 + 1];
  int i1 = btiT[(m * NBLK + t) * 2 + 0];
  int i2 = btiT[(m * NBLK + t) * 2 + 1];
  merge2(b1, i1, b2, i2,
         btvT[(m * NBLK + t + 256) * 2 + 0], btiT[(m * NBLK + t + 256) * 2 + 0],
         btvT[(m * NBLK + t + 256) * 2 + 1], btiT[(m * NBLK + t + 256) * 2 + 1]);
  __shared__ float s1[256], s2[256];
  __shared__ int t1[256], t2[256];
  s1[t] = b1; s2[t] = b2; t1[t] = i1; t2[t] = i2;
  __syncthreads();
  for (int o = 128; o > 0; o >>= 1) {
    if (t < o) {
      float a1 = s1[t], a2 = s2[t];
      int ai1 = t1[t], ai2 = t2[t];
      merge2(a1, ai1, a2, ai2, s1[t + o], t1[t + o], s2[t + o], t2[t + o]);
      s1[t] = a1; t1[t] = ai1; s2[t] = a2; t2[t] = ai2;
    }
    __syncthreads();
  }
  if (t == 0) {
    colti[2 * m] = t1[0];
    colti[2 * m + 1] = t2[0];
  }
}

// ---- gather negatives
__global__ __launch_bounds__(256) void k_gather(const float* __restrict__ E,
                                                const int* __restrict__ negidx,
                                                const int* __restrict__ colti,
                                                float* __restrict__ out) {
#pragma unroll
  for (int k = 0; k < 4; ++k) {
    int idx = (blockIdx.x * 4 + k) * 256 + threadIdx.x;
    int row = idx >> 7, d = idx & 127;
    int m = negidx[row];
    int j1 = colti[2 * m], j2 = colti[2 * m + 1];
    int j = (j1 != row) ? j1 : j2;
    out[(size_t)(KK * DD) + (size_t)row * DD + d] = E[(size_t)j * DD + d];
  }
}

extern "C" void kernel_launch(void* const* d_in, const int* in_sizes, int n_in,
                              void* d_out, int out_size, void* d_ws, size_t ws_size,
                              hipStream_t stream) {
  const float* E = (const float*)d_in[0];
  const float* C0 = (const float*)d_in[1];
  float* out = (float*)d_out;

  float* wsf = (float*)d_ws;
  float* chatG0 = wsf;                              // 8192
  float* chatG1 = chatG0 + KK * DD;                 // 8192
  float* cbb0 = chatG1 + KK * DD;                   // 8192
  float* cbb1 = cbb0 + KK * DD;                     // 8192
  float* updb = cbb1 + KK * DD;                     // 8192
  float* uhat = updb + KK * DD;                     // 8192
  float* n2b = uhat + KK * DD;                      // 64
  float* partial = n2b + KK;                        // [512][64][128] = 16 MB
  int* pcountT = (int*)(partial + (size_t)NBLK * KK * DD);  // 64*512
  int* negidx = pcountT + KK * NBLK;                // NN
  int* colti = negidx + NN;                         // 128
  float* btvT = (float*)(colti + 128);              // 64*512*2
  int* btiT = (int*)(btvT + KK * NBLK * 2);         // 64*512*2

  float* chatG[2] = {chatG0, chatG1};
  float* cbb[2] = {cbb0, cbb1};

  for (int it = 0; it < N_ITERS; ++it) {
    const float* chatR = (it == 0) ? chatG0 : chatG[(it - 1) & 1];
    float* chatW = chatG[it & 1];
    const float* cbPrev = (it <= 1) ? C0 : cbb[(it - 1) & 1];
    float* cbW = cbb[it & 1];
    k_sim<0><<<NBLK, 256, 0, stream>>>(E, C0, chatR, chatW, cbPrev, cbW, updb,
                                       uhat, n2b, it, partial, pcountT,
                                       nullptr, nullptr, nullptr, nullptr);
    const float* cbR = (it == 0) ? C0 : cbb[it & 1];
    k_red<<<KK, 1024, 0, stream>>>(cbR, partial, pcountT, updb, uhat, n2b);
  }
  // final: select c_10 (block0 -> out), sim, negidx, per-block top2
  k_sim<1><<<NBLK, 256, 0, stream>>>(E, C0, chatG[(N_ITERS - 1) & 1], nullptr,
                                     cbb[(N_ITERS - 1) & 1], nullptr, updb, uhat,
                                     n2b, N_ITERS, nullptr, nullptr,
                                     negidx, btvT, btiT, out);
  k_top<<<KK, 256, 0, stream>>>(btvT, btiT, colti);
  k_gather<<<NN * DD / 1024, 256, 0, stream>>>(E, negidx, colti, out);
}